// Round 3
// baseline (3360.887 us; speedup 1.0000x reference)
//
#include <hip/hip_runtime.h>

// Bitwise-mimic of the numpy fp32 finite-difference reference.
// v3: tanh computed in f64 then rounded to f32 (≈correctly rounded) to track
// numpy's SIMD tanhf as closely as possible without its exact table — the
// wrong-h-bits cascade was capping rounding correlation with the reference.
// Also: fixed cross-wave race in Gauss-Jordan (added trailing barrier).
//
// Chain model (OpenBLAS): every dot = sequential ascending-k fmaf from 0;
// h@W2 (K=512) has one partial-sum boundary at k=384 (KC); bias adds and
// +eye are separate fp32 adds; FD divide by fl32(2*1e-4f).

#define HH 512
#define DD 256
#define EPSF 1e-4f
#define TWOEPS (2.0f * 1e-4f)   // == fl32(2e-4) exactly (0x3951B717 is nearest)
#define NT 16          // 16 tiles x 32 rows = 512 (K of h@W2)
#define KT1 12         // tiles 0..11 = k<384 (segment 1), 12..15 = segment 2

__global__ __launch_bounds__(256, 1)
void christoffel_mimic(const float* __restrict__ z,
                       const float* __restrict__ W1,
                       const float* __restrict__ b1,
                       const float* __restrict__ W2,
                       const float* __restrict__ b2,
                       float* __restrict__ out)
{
    __shared__ __align__(16) float hS[33][HH];    // 67.6 KB: tanh activations per eval
    __shared__ __align__(16) float wS[16384];     // 64 KB: W2 tile dbuf; later A rows + dg
    __shared__ float gaug[16 * 36];               // [g | I] augmented for Gauss-Jordan
    __shared__ float zS[16];

    const int tid  = threadIdx.x;
    const int pt   = blockIdx.x;
    const int w    = tid >> 6;          // wave 0..3
    const int lane = tid & 63;
    const int c4   = lane * 4;          // 4 output cols per lane (covers 256)

    if (tid < 16) zS[tid] = z[pt * 16 + tid];
    __syncthreads();

    // ================= Phase 1: h for all 33 evals =================
    // eval e<32: dir p=e>>1, sign +(e even)/-(e odd); e=32: central.
    {
        float w1c[2][16], b1v[2], zr[16];
        #pragma unroll
        for (int d = 0; d < 16; ++d) {
            w1c[0][d] = W1[d * HH + tid];
            w1c[1][d] = W1[d * HH + tid + 256];
        }
        b1v[0] = b1[tid]; b1v[1] = b1[tid + 256];
        #pragma unroll
        for (int d = 0; d < 16; ++d) zr[d] = zS[d];

        for (int e = 0; e < 33; ++e) {
            const int p = (e < 32) ? (e >> 1) : -1;
            float zp = 0.0f;
            if (p >= 0) {
                const float zb = zS[p];
                zp = (e & 1) ? (zb - EPSF) : (zb + EPSF);
            }
            #pragma unroll
            for (int jj = 0; jj < 2; ++jj) {
                float a = 0.0f;
                #pragma unroll
                for (int d = 0; d < 16; ++d) {
                    const float zd = (d == p) ? zp : zr[d];
                    a = fmaf(zd, w1c[jj][d], a);   // ascending-d chain (sgemm K=16)
                }
                a = a + b1v[jj];                    // separate bias add (b1=0: exact)
                // f64 tanh rounded to f32: <=0.5ulp vs true tanh -> closest
                // achievable tracking of numpy's SIMD tanhf bits.
                hS[e][tid + jj * 256] = (float)tanh((double)a);
            }
        }
    }
    __syncthreads();

    // ================= Phase 2: A = h @ W2 (+b2), bitwise chains =================
    // wave w handles evals e = w*8 .. w*8+7; slot 8 = central (wave 0 writes).
    int hrow[9];
    #pragma unroll
    for (int i = 0; i < 8; ++i) hrow[i] = w * 8 + i;
    hrow[8] = 32;

    float acc1[9][4], acc2[9][4];
    #pragma unroll
    for (int i = 0; i < 9; ++i)
        #pragma unroll
        for (int q = 0; q < 4; ++q) { acc1[i][q] = 0.0f; acc2[i][q] = 0.0f; }

    // prologue: stage tile 0
    {
        float4 stg[8];
        #pragma unroll
        for (int it = 0; it < 8; ++it)
            stg[it] = *reinterpret_cast<const float4*>(&W2[it * 1024 + tid * 4]);
        #pragma unroll
        for (int it = 0; it < 8; ++it)
            *reinterpret_cast<float4*>(&wS[it * 1024 + tid * 4]) = stg[it];
    }
    __syncthreads();

    auto do_tile = [&](int t, float (&A)[9][4]) {
        float4 stg[8];
        const bool has_next = (t + 1 < NT);
        if (has_next) {
            #pragma unroll
            for (int it = 0; it < 8; ++it)
                stg[it] = *reinterpret_cast<const float4*>(&W2[(t + 1) * 8192 + it * 1024 + tid * 4]);
        }
        const float* wbuf = &wS[(t & 1) * 8192];
        const int jbase = t * 32;
        #pragma unroll
        for (int jj4 = 0; jj4 < 8; ++jj4) {
            float4 w2r[4];
            #pragma unroll
            for (int r = 0; r < 4; ++r)
                w2r[r] = *reinterpret_cast<const float4*>(&wbuf[(jj4 * 4 + r) * DD + c4]);
            float4 hr[9];
            #pragma unroll
            for (int i = 0; i < 9; ++i)
                hr[i] = *reinterpret_cast<const float4*>(&hS[hrow[i]][jbase + jj4 * 4]);
            #pragma unroll
            for (int i = 0; i < 9; ++i) {
                A[i][0] = fmaf(hr[i].x, w2r[0].x, A[i][0]);
                A[i][1] = fmaf(hr[i].x, w2r[0].y, A[i][1]);
                A[i][2] = fmaf(hr[i].x, w2r[0].z, A[i][2]);
                A[i][3] = fmaf(hr[i].x, w2r[0].w, A[i][3]);
                A[i][0] = fmaf(hr[i].y, w2r[1].x, A[i][0]);
                A[i][1] = fmaf(hr[i].y, w2r[1].y, A[i][1]);
                A[i][2] = fmaf(hr[i].y, w2r[1].z, A[i][2]);
                A[i][3] = fmaf(hr[i].y, w2r[1].w, A[i][3]);
                A[i][0] = fmaf(hr[i].z, w2r[2].x, A[i][0]);
                A[i][1] = fmaf(hr[i].z, w2r[2].y, A[i][1]);
                A[i][2] = fmaf(hr[i].z, w2r[2].z, A[i][2]);
                A[i][3] = fmaf(hr[i].z, w2r[2].w, A[i][3]);
                A[i][0] = fmaf(hr[i].w, w2r[3].x, A[i][0]);
                A[i][1] = fmaf(hr[i].w, w2r[3].y, A[i][1]);
                A[i][2] = fmaf(hr[i].w, w2r[3].z, A[i][2]);
                A[i][3] = fmaf(hr[i].w, w2r[3].w, A[i][3]);
            }
        }
        if (has_next) {
            #pragma unroll
            for (int it = 0; it < 8; ++it)
                *reinterpret_cast<float4*>(&wS[((t + 1) & 1) * 8192 + it * 1024 + tid * 4]) = stg[it];
        }
        __syncthreads();
    };

    for (int t = 0; t < KT1; ++t) do_tile(t, acc1);   // k = 0..383
    for (int t = KT1; t < NT; ++t) do_tile(t, acc2);  // k = 384..511

    // finalize A: fl(fl(S1)+S2) + b2  (b2=0: exact), write rows (eval ids)
    {
        const float4 b2v = *reinterpret_cast<const float4*>(&b2[c4]);
        #pragma unroll
        for (int i = 0; i < 9; ++i) {
            if (i < 8 || w == 0) {
                float4 av;
                av.x = (acc1[i][0] + acc2[i][0]) + b2v.x;
                av.y = (acc1[i][1] + acc2[i][1]) + b2v.y;
                av.z = (acc1[i][2] + acc2[i][2]) + b2v.z;
                av.w = (acc1[i][3] + acc2[i][3]) + b2v.w;
                *reinterpret_cast<float4*>(&wS[hrow[i] * DD + c4]) = av;
            }
        }
    }
    __syncthreads();

    // ============ Phase 3: grams, FD difference, central inverse ============
    const int m = tid >> 4, n = tid & 15;

    // central g -> gaug = [g | I]
    {
        const float* AC = &wS[32 * DD];
        float s = 0.0f;
        #pragma unroll
        for (int k = 0; k < 16; ++k) s = fmaf(AC[m * 16 + k], AC[n * 16 + k], s);
        if (m == n) s = s + 1.0f;
        gaug[m * 36 + n]      = s;
        gaug[m * 36 + 16 + n] = (m == n) ? 1.0f : 0.0f;
    }

    // dg[p][m][n] = (g_p - g_m) / 2eps  (gram asc-k + eye, subtract, divide)
    float* dgL = &wS[33 * DD];   // 4096 floats at offset 8448
    for (int p = 0; p < 16; ++p) {
        const float* Ap = &wS[(2 * p) * DD];
        const float* Am = &wS[(2 * p + 1) * DD];
        float sp = 0.0f, sm = 0.0f;
        #pragma unroll
        for (int k = 0; k < 16; ++k) sp = fmaf(Ap[m * 16 + k], Ap[n * 16 + k], sp);
        #pragma unroll
        for (int k = 0; k < 16; ++k) sm = fmaf(Am[m * 16 + k], Am[n * 16 + k], sm);
        if (m == n) { sp = sp + 1.0f; sm = sm + 1.0f; }
        dgL[p * DD + m * 16 + n] = (sp - sm) / TWOEPS;
    }
    __syncthreads();

    // Gauss-Jordan inverse of central g (SPD, no pivoting). Double-barrier
    // per iteration: reads | sync | writes | sync  (fixes cross-wave race).
    {
        const int i  = tid >> 4;
        const int cA = (tid & 15);
        const int cB = (tid & 15) + 16;
        for (int k = 0; k < 16; ++k) {
            const float pv  = gaug[k * 36 + k];
            const float f   = gaug[i * 36 + k];
            const float rkA = gaug[k * 36 + cA];
            const float rkB = gaug[k * 36 + cB];
            const float giA = gaug[i * 36 + cA];
            const float giB = gaug[i * 36 + cB];
            __syncthreads();
            const float invp = 1.0f / pv;
            if (i == k) {
                gaug[i * 36 + cA] = rkA * invp;
                gaug[i * 36 + cB] = rkB * invp;
            } else {
                const float fp = f * invp;
                gaug[i * 36 + cA] = giA - fp * rkA;
                gaug[i * 36 + cB] = giB - fp * rkB;
            }
            __syncthreads();
        }
    }

    // ============ Phase 4: T, Gamma, store ============
    float* Tp = &hS[0][0];   // h region dead; reuse 4096 floats
    {
        const int i = tid >> 4, jj = tid & 15;
        float t[16];
        for (int mm = 0; mm < 16; ++mm) {
            t[mm] = dgL[i * DD + jj * 16 + mm]
                  + dgL[jj * DD + i * 16 + mm]
                  - dgL[mm * DD + i * 16 + jj];
        }
        #pragma unroll
        for (int mm = 0; mm < 16; ++mm) Tp[i * DD + jj * 16 + mm] = t[mm];
    }
    __syncthreads();

    {
        const int k = tid >> 4, i = tid & 15;
        float gk[16];
        #pragma unroll
        for (int mm = 0; mm < 16; ++mm) gk[mm] = gaug[k * 36 + 16 + mm];
        float gout[16];
        for (int j = 0; j < 16; ++j) {
            const float* Tv = &Tp[i * DD + j * 16];
            float s = 0.0f;
            #pragma unroll
            for (int mm = 0; mm < 16; ++mm) s = fmaf(gk[mm], Tv[mm], s);
            gout[j] = 0.5f * s;
        }
        float4* dst = reinterpret_cast<float4*>(&out[(size_t)pt * 4096 + (size_t)tid * 16]);
        #pragma unroll
        for (int q = 0; q < 4; ++q) dst[q] = *reinterpret_cast<const float4*>(&gout[q * 4]);
    }
}

extern "C" void kernel_launch(void* const* d_in, const int* in_sizes, int n_in,
                              void* d_out, int out_size, void* d_ws, size_t ws_size,
                              hipStream_t stream) {
    const float* z  = (const float*)d_in[0];
    const float* W1 = (const float*)d_in[1];
    const float* b1 = (const float*)d_in[2];
    const float* W2 = (const float*)d_in[3];
    const float* b2 = (const float*)d_in[4];
    float* out = (float*)d_out;
    const int npts = in_sizes[0] / 16;   // B*L = 8192
    christoffel_mimic<<<npts, 256, 0, stream>>>(z, W1, b1, W2, b2, out);
}